// Round 2
// baseline (5982.905 us; speedup 1.0000x reference)
//
#include <hip/hip_runtime.h>
#include <math.h>

#define NNODES 100000

// ---------- order-preserving float <-> uint encoding for atomicMax ----------
__device__ __forceinline__ unsigned int encf(float f) {
  unsigned int u = __float_as_uint(f);
  return (u & 0x80000000u) ? ~u : (u | 0x80000000u);
}
__device__ __forceinline__ float decf(unsigned int k) {
  unsigned int u = (k & 0x80000000u) ? (k ^ 0x80000000u) : ~k;
  return __uint_as_float(u);
}

// edge e -> (src, dst); e >= E are self loops
__device__ __forceinline__ void edge_sd(const int* __restrict__ ei, int E, int e,
                                        int& s, int& d) {
  if (e < E) { s = ei[e]; d = ei[E + e]; }
  else { s = e - E; d = s; }
}

// ---------- GEMM: out[n, ncols] = in[n, 64] @ W[64, col0:col0+ncols] ----------
__global__ __launch_bounds__(256) void gemm_cols(const float* __restrict__ in,
                                                 const float* __restrict__ W,
                                                 float* __restrict__ out,
                                                 int n, int fo, int col0, int ncols) {
  __shared__ float sW[64][64];
  __shared__ float sX[16][64];
  int ct = blockIdx.y * 64;
  for (int i = threadIdx.x; i < 64 * 64; i += 256) {
    int k = i >> 6, c = i & 63;
    sW[k][c] = W[k * fo + col0 + ct + c];
  }
  int r0 = blockIdx.x * 16;
  for (int i = threadIdx.x; i < 16 * 64; i += 256) {
    int r = i >> 6, k = i & 63;
    sX[r][k] = (r0 + r < n) ? in[(size_t)(r0 + r) * 64 + k] : 0.f;
  }
  __syncthreads();
  int c = threadIdx.x & 63;
  int rr = threadIdx.x >> 6;
#pragma unroll
  for (int rsub = 0; rsub < 4; ++rsub) {
    int r = rr * 4 + rsub;
    float acc = 0.f;
#pragma unroll
    for (int k = 0; k < 64; ++k) acc += sX[r][k] * sW[k][c];
    if (r0 + r < n) out[(size_t)(r0 + r) * ncols + ct + c] = acc;
  }
}

// ---------- init M (enc(-inf)) and S (0) ----------
__global__ void init_ms(unsigned int* __restrict__ M, float* __restrict__ S, int n) {
  int i = blockIdx.x * blockDim.x + threadIdx.x;
  if (i < n) { M[i] = 0x007FFFFFu; S[i] = 0.f; }
}

__global__ void zerof(float* __restrict__ p, int n) {
  int i = blockIdx.x * blockDim.x + threadIdx.x;
  if (i < n) p[i] = 0.f;
}

// ---------- logits, C=8 (layers 0/1): one thread per (edge, head) ----------
__global__ __launch_bounds__(256) void logits_c8(const float* __restrict__ xl,
                                                 const float* __restrict__ xr,
                                                 const float* __restrict__ att, // [8][8]
                                                 const int* __restrict__ ei, int E, int ne,
                                                 float* __restrict__ logbuf,
                                                 unsigned int* __restrict__ M) {
  __shared__ float sa[64];
  if (threadIdx.x < 64) sa[threadIdx.x] = att[threadIdx.x];
  __syncthreads();
  int i = blockIdx.x * blockDim.x + threadIdx.x;
  if (i >= ne * 8) return;
  int e = i >> 3, h = i & 7;
  int s, d;
  edge_sd(ei, E, e, s, d);
  const float* pl = xl + (size_t)s * 64 + h * 8;
  const float* pr = xr + (size_t)d * 64 + h * 8;
  float acc = 0.f;
#pragma unroll
  for (int c = 0; c < 8; ++c) {
    float m = pl[c] + pr[c];
    float v = m > 0.f ? m : 0.2f * m;
    acc += v * sa[h * 8 + c];
  }
  logbuf[i] = acc;
  atomicMax(&M[d * 8 + h], encf(acc));
}

// ---------- logits, layer 2, head-blocked: one wave per edge ----------
__global__ __launch_bounds__(256) void logits2(const float* __restrict__ xl,
                                               const float* __restrict__ xr,
                                               const float* __restrict__ att, // [8][64]
                                               const int* __restrict__ ei, int E, int ne,
                                               float* __restrict__ logbuf,
                                               unsigned int* __restrict__ M,
                                               int h0, int nh) {
  int wave = (int)(((size_t)blockIdx.x * blockDim.x + threadIdx.x) >> 6);
  int lane = threadIdx.x & 63;
  if (wave >= ne) return;
  int s, d;
  edge_sd(ei, E, wave, s, d);
  const float* pl = xl + (size_t)s * (nh * 64);
  const float* pr = xr + (size_t)d * (nh * 64);
  float keep = 0.f;
  for (int j = 0; j < nh; ++j) {
    float m = pl[j * 64 + lane] + pr[j * 64 + lane];
    float v = m > 0.f ? m : 0.2f * m;
    float t = v * att[(h0 + j) * 64 + lane];
#pragma unroll
    for (int o = 32; o; o >>= 1) t += __shfl_xor(t, o);
    if (lane == j) keep = t;
  }
  if (lane < nh) {
    logbuf[(size_t)wave * 8 + h0 + lane] = keep;
    atomicMax(&M[d * 8 + h0 + lane], encf(keep));
  }
}

// ---------- exp(l - max) and segment sum; overwrites logbuf with p ----------
__global__ __launch_bounds__(256) void expsum(float* __restrict__ logbuf,
                                              const unsigned int* __restrict__ M,
                                              float* __restrict__ S,
                                              const int* __restrict__ ei, int E, int ne) {
  int i = blockIdx.x * blockDim.x + threadIdx.x;
  if (i >= ne * 8) return;
  int e = i >> 3, h = i & 7;
  int s, d;
  edge_sd(ei, E, e, s, d);
  float m = decf(M[d * 8 + h]);
  float p = expf(logbuf[i] - m);
  logbuf[i] = p;
  atomicAdd(&S[d * 8 + h], p);
}

// ---------- scatter, C=8 concat: one wave per edge, lane = h*8+c ----------
__global__ __launch_bounds__(256) void scatter_c8(const float* __restrict__ xl,
                                                  const float* __restrict__ logbuf,
                                                  const float* __restrict__ S,
                                                  const int* __restrict__ ei, int E, int ne,
                                                  float* __restrict__ acc) {
  int wave = (int)(((size_t)blockIdx.x * blockDim.x + threadIdx.x) >> 6);
  int lane = threadIdx.x & 63;
  if (wave >= ne) return;
  int s, d;
  edge_sd(ei, E, wave, s, d);
  int h = lane >> 3;
  float p = logbuf[(size_t)wave * 8 + h];
  float sum = S[d * 8 + h];
  float alpha = p / (sum + 1e-16f);
  float v = alpha * xl[(size_t)s * 64 + lane];
  atomicAdd(&acc[(size_t)d * 64 + lane], v);
}

// ---------- scatter, layer 2 head-blocked, mean-over-heads ----------
__global__ __launch_bounds__(256) void scatter2(const float* __restrict__ xl,
                                                const float* __restrict__ logbuf,
                                                const float* __restrict__ S,
                                                const int* __restrict__ ei, int E, int ne,
                                                float* __restrict__ acc,
                                                int h0, int nh) {
  int wave = (int)(((size_t)blockIdx.x * blockDim.x + threadIdx.x) >> 6);
  int lane = threadIdx.x & 63;
  if (wave >= ne) return;
  int s, d;
  edge_sd(ei, E, wave, s, d);
  float v = 0.f;
  for (int j = 0; j < nh; ++j) {
    float alpha = logbuf[(size_t)wave * 8 + h0 + j] / (S[d * 8 + h0 + j] + 1e-16f);
    v += alpha * xl[(size_t)s * (nh * 64) + j * 64 + lane];
  }
  atomicAdd(&acc[(size_t)d * 64 + lane], v * 0.125f);
}

// ---------- epilogue: mode 0: elu(acc+b); 1: elu(acc+b)+res; 2: acc+b ----------
__global__ __launch_bounds__(256) void epilogue(const float* __restrict__ acc,
                                                const float* __restrict__ b,
                                                const float* __restrict__ res,
                                                float* __restrict__ out,
                                                int n, int mode) {
  int i = blockIdx.x * blockDim.x + threadIdx.x;
  if (i >= n) return;
  float v = acc[i] + b[i & 63];
  if (mode != 2) v = v > 0.f ? v : expm1f(v);
  if (mode == 1) v += res[i];
  out[i] = v;
}

extern "C" void kernel_launch(void* const* d_in, const int* in_sizes, int n_in,
                              void* d_out, int out_size, void* d_ws, size_t ws_size,
                              hipStream_t stream) {
  const float* x = (const float*)d_in[0];
  const int* ei = (const int*)d_in[1];
  const float* Wmat[3][2] = {
      {(const float*)d_in[2], (const float*)d_in[3]},
      {(const float*)d_in[6], (const float*)d_in[7]},
      {(const float*)d_in[10], (const float*)d_in[11]}};
  const float* att[3] = {(const float*)d_in[4], (const float*)d_in[8],
                         (const float*)d_in[12]};
  const float* bias[3] = {(const float*)d_in[5], (const float*)d_in[9],
                          (const float*)d_in[13]};
  int E = in_sizes[1] / 2;
  int ne = E + NNODES;

  // choose head-block so workspace fits ws_size
  int NHB = 8;
  for (;;) {
    size_t elems = (size_t)NNODES * (2 * (size_t)NHB * 64 + 8 + 8 + 64 + 64) +
                   (size_t)ne * 8;
    if (elems * 4 <= ws_size || NHB == 1) break;
    NHB >>= 1;
  }
  int nblk = 8 / NHB;

  float* ws = (float*)d_ws;
  size_t off = 0;
  float* XL = ws + off; off += (size_t)NNODES * NHB * 64;
  float* XR = ws + off; off += (size_t)NNODES * NHB * 64;
  float* LOG = ws + off; off += (size_t)ne * 8;
  unsigned int* M = (unsigned int*)(ws + off); off += (size_t)NNODES * 8;
  float* S = ws + off; off += (size_t)NNODES * 8;
  float* CUR = ws + off; off += (size_t)NNODES * 64;
  float* ACC = ws + off; off += (size_t)NNODES * 64;

  const int gx16 = (NNODES + 15) / 16;
  const int ewaves = (ne + 3) / 4;  // blocks of 256 = 4 waves

  // ---------------- layers 0 and 1 (C=8, concat) ----------------
  for (int layer = 0; layer < 2; ++layer) {
    const float* in = (layer == 0) ? x : CUR;
    gemm_cols<<<dim3(gx16, 1), 256, 0, stream>>>(in, Wmat[layer][0], XL, NNODES, 64, 0, 64);
    gemm_cols<<<dim3(gx16, 1), 256, 0, stream>>>(in, Wmat[layer][1], XR, NNODES, 64, 0, 64);
    init_ms<<<(NNODES * 8 + 255) / 256, 256, 0, stream>>>(M, S, NNODES * 8);
    zerof<<<(NNODES * 64 + 255) / 256, 256, 0, stream>>>(ACC, NNODES * 64);

    logits_c8<<<(ne * 8 + 255) / 256, 256, 0, stream>>>(XL, XR, att[layer], ei, E, ne, LOG, M);
    expsum<<<(ne * 8 + 255) / 256, 256, 0, stream>>>(LOG, M, S, ei, E, ne);
    scatter_c8<<<ewaves, 256, 0, stream>>>(XL, LOG, S, ei, E, ne, ACC);

    epilogue<<<(NNODES * 64 + 255) / 256, 256, 0, stream>>>(
        ACC, bias[layer], CUR, CUR, NNODES * 64, layer == 0 ? 0 : 1);
  }

  // ---------------- layer 2 (C=64, mean over heads) ----------------
  init_ms<<<(NNODES * 8 + 255) / 256, 256, 0, stream>>>(M, S, NNODES * 8);
  zerof<<<(NNODES * 64 + 255) / 256, 256, 0, stream>>>(ACC, NNODES * 64);

  for (int hb = 0; hb < nblk; ++hb) {
    gemm_cols<<<dim3(gx16, NHB), 256, 0, stream>>>(CUR, Wmat[2][0], XL, NNODES, 512,
                                                   hb * NHB * 64, NHB * 64);
    gemm_cols<<<dim3(gx16, NHB), 256, 0, stream>>>(CUR, Wmat[2][1], XR, NNODES, 512,
                                                   hb * NHB * 64, NHB * 64);
    logits2<<<ewaves, 256, 0, stream>>>(XL, XR, att[2], ei, E, ne, LOG, M, hb * NHB, NHB);
  }
  expsum<<<(ne * 8 + 255) / 256, 256, 0, stream>>>(LOG, M, S, ei, E, ne);
  for (int hb = 0; hb < nblk; ++hb) {
    if (nblk > 1)
      gemm_cols<<<dim3(gx16, NHB), 256, 0, stream>>>(CUR, Wmat[2][0], XL, NNODES, 512,
                                                     hb * NHB * 64, NHB * 64);
    scatter2<<<ewaves, 256, 0, stream>>>(XL, LOG, S, ei, E, ne, ACC, hb * NHB, NHB);
  }
  epilogue<<<(NNODES * 64 + 255) / 256, 256, 0, stream>>>(
      ACC, bias[2], CUR, (float*)d_out, NNODES * 64, 2);
}

// Round 3
// 4060.824 us; speedup vs baseline: 1.4733x; 1.4733x over previous
//
#include <hip/hip_runtime.h>
#include <math.h>

#define NNODES 100000
typedef unsigned short bf16_t;

// ---------- order-preserving float <-> uint encoding for atomicMax ----------
__device__ __forceinline__ unsigned int encf(float f) {
  unsigned int u = __float_as_uint(f);
  return (u & 0x80000000u) ? ~u : (u | 0x80000000u);
}
__device__ __forceinline__ float decf(unsigned int k) {
  unsigned int u = (k & 0x80000000u) ? (k ^ 0x80000000u) : ~k;
  return __uint_as_float(u);
}

// ---------- bf16 helpers ----------
__device__ __forceinline__ float bfu(bf16_t u) { return __uint_as_float(((unsigned)u) << 16); }
__device__ __forceinline__ float bf_lo(unsigned u) { return __uint_as_float(u << 16); }
__device__ __forceinline__ float bf_hi(unsigned u) { return __uint_as_float(u & 0xffff0000u); }
__device__ __forceinline__ bf16_t f2bf(float f) {
  unsigned u = __float_as_uint(f);
  return (bf16_t)((u + 0x7fffu + ((u >> 16) & 1u)) >> 16);
}

// edge e -> (src, dst); e >= E are self loops
__device__ __forceinline__ void edge_sd(const int* __restrict__ ei, int E, int e,
                                        int& s, int& d) {
  if (e < E) { s = ei[e]; d = ei[E + e]; }
  else { s = e - E; d = s; }
}

// ---------- GEMM: out[n, ncols](bf16) = in[n, 64] @ W[64, col0:col0+ncols] ----------
__global__ __launch_bounds__(256) void gemm_cols(const float* __restrict__ in,
                                                 const float* __restrict__ W,
                                                 bf16_t* __restrict__ out,
                                                 int n, int fo, int col0, int ncols) {
  __shared__ float sW[64][64];
  __shared__ float sX[16][64];
  int ct = blockIdx.y * 64;
  for (int i = threadIdx.x; i < 64 * 64; i += 256) {
    int k = i >> 6, c = i & 63;
    sW[k][c] = W[k * fo + col0 + ct + c];
  }
  int r0 = blockIdx.x * 16;
  for (int i = threadIdx.x; i < 16 * 64; i += 256) {
    int r = i >> 6, k = i & 63;
    sX[r][k] = (r0 + r < n) ? in[(size_t)(r0 + r) * 64 + k] : 0.f;
  }
  __syncthreads();
  int c = threadIdx.x & 63;
  int rr = threadIdx.x >> 6;
#pragma unroll
  for (int rsub = 0; rsub < 4; ++rsub) {
    int r = rr * 4 + rsub;
    float acc = 0.f;
#pragma unroll
    for (int k = 0; k < 64; ++k) acc += sX[r][k] * sW[k][c];
    if (r0 + r < n) out[(size_t)(r0 + r) * ncols + ct + c] = f2bf(acc);
  }
}

// ---------- init M (enc(-inf)) and S (0) ----------
__global__ void init_ms(unsigned int* __restrict__ M, float* __restrict__ S, int n) {
  int i = blockIdx.x * blockDim.x + threadIdx.x;
  if (i < n) { M[i] = 0x007FFFFFu; S[i] = 0.f; }
}
__global__ void zerof(float* __restrict__ p, int n) {
  int i = blockIdx.x * blockDim.x + threadIdx.x;
  if (i < n) p[i] = 0.f;
}

// ---------- logits, C=8 (layers 0/1): one thread per (edge, head) ----------
__global__ __launch_bounds__(256) void logits_c8(const bf16_t* __restrict__ xl,
                                                 const bf16_t* __restrict__ xr,
                                                 const float* __restrict__ att, // [8][8]
                                                 const int* __restrict__ ei, int E, int ne,
                                                 float* __restrict__ logbuf,
                                                 unsigned int* __restrict__ M) {
  __shared__ float sa[64];
  if (threadIdx.x < 64) sa[threadIdx.x] = att[threadIdx.x];
  __syncthreads();
  int i = blockIdx.x * blockDim.x + threadIdx.x;
  if (i >= ne * 8) return;
  int e = i >> 3, h = i & 7;
  int s, d;
  edge_sd(ei, E, e, s, d);
  uint4 ql = ((const uint4*)xl)[(size_t)s * 8 + h];
  uint4 qr = ((const uint4*)xr)[(size_t)d * 8 + h];
  unsigned lw[4] = {ql.x, ql.y, ql.z, ql.w};
  unsigned rw[4] = {qr.x, qr.y, qr.z, qr.w};
  const float* pa = &sa[h * 8];
  float acc = 0.f;
#pragma unroll
  for (int j = 0; j < 4; ++j) {
    float m0 = bf_lo(lw[j]) + bf_lo(rw[j]);
    float m1 = bf_hi(lw[j]) + bf_hi(rw[j]);
    m0 = m0 > 0.f ? m0 : 0.2f * m0;
    m1 = m1 > 0.f ? m1 : 0.2f * m1;
    acc += m0 * pa[2 * j] + m1 * pa[2 * j + 1];
  }
  logbuf[i] = acc;
  atomicMax(&M[d * 8 + h], encf(acc));
}

// ---------- scatter+exp+sum, C=8 (layers 0/1): one wave per edge ----------
__global__ __launch_bounds__(256) void scatter_c8(const bf16_t* __restrict__ xl,
                                                  const float* __restrict__ logbuf,
                                                  const unsigned int* __restrict__ M,
                                                  float* __restrict__ S,
                                                  const int* __restrict__ ei, int E, int ne,
                                                  float* __restrict__ acc) {
  int wave = (int)((blockIdx.x * 256u + threadIdx.x) >> 6);
  int l = threadIdx.x & 63;
  if (wave >= ne) return;
  int s, d;
  edge_sd(ei, E, wave, s, d);
  float p = 0.f;
  if (l < 8) {
    float m = decf(M[d * 8 + l]);
    p = expf(logbuf[(size_t)wave * 8 + l] - m);
    atomicAdd(&S[d * 8 + l], p);
  }
  float ph = __shfl(p, l >> 3);
  float x = bfu(xl[(size_t)s * 64 + l]);
  atomicAdd(&acc[(size_t)d * 64 + l], ph * x);
}

// ---------- epilogue layers 0/1: divide by S, bias, ELU, optional residual ----------
__global__ __launch_bounds__(256) void epi01(const float* __restrict__ acc,
                                             const float* __restrict__ S,
                                             const float* __restrict__ b,
                                             const float* __restrict__ res,
                                             float* __restrict__ out,
                                             int n, int addres) {
  int i = blockIdx.x * blockDim.x + threadIdx.x;
  if (i >= n) return;
  int c = i & 63;
  float s = S[(i >> 6) * 8 + (c >> 3)];
  float v = acc[i] / (s + 1e-16f) + b[c];
  v = v > 0.f ? v : expm1f(v);
  if (addres) v += res[i];
  out[i] = v;
}

// ---------- logits layer 2, head-blocked: 8 lanes per (edge, head) ----------
__global__ __launch_bounds__(256) void logits2(const bf16_t* __restrict__ xl,
                                               const bf16_t* __restrict__ xr,
                                               const float* __restrict__ att, // [8][64]
                                               const int* __restrict__ ei, int E, int ne,
                                               float* __restrict__ logbuf,
                                               unsigned int* __restrict__ M,
                                               int h0, int nh) {
  __shared__ float sa[512];
  for (int i = threadIdx.x; i < 512; i += 256) sa[i] = att[i];
  __syncthreads();
  int l = threadIdx.x & 63;
  int wave = (int)((blockIdx.x * 256u + threadIdx.x) >> 6);
  int grp = nh * 8;           // lanes per edge
  int epw = 64 / grp;         // edges per wave
  int esub = l / grp;
  int r = l - esub * grp;
  int h = r >> 3, c0 = (r & 7) * 8;
  int e = wave * epw + esub;
  if (e >= ne) return;
  int s, d;
  edge_sd(ei, E, e, s, d);
  int stride = nh * 64;
  uint4 ql = *(const uint4*)(xl + (size_t)s * stride + h * 64 + c0);
  uint4 qr = *(const uint4*)(xr + (size_t)d * stride + h * 64 + c0);
  unsigned lw[4] = {ql.x, ql.y, ql.z, ql.w};
  unsigned rw[4] = {qr.x, qr.y, qr.z, qr.w};
  const float* pa = &sa[(h0 + h) * 64 + c0];
  float acc = 0.f;
#pragma unroll
  for (int j = 0; j < 4; ++j) {
    float m0 = bf_lo(lw[j]) + bf_lo(rw[j]);
    float m1 = bf_hi(lw[j]) + bf_hi(rw[j]);
    m0 = m0 > 0.f ? m0 : 0.2f * m0;
    m1 = m1 > 0.f ? m1 : 0.2f * m1;
    acc += m0 * pa[2 * j] + m1 * pa[2 * j + 1];
  }
#pragma unroll
  for (int o = 1; o < 8; o <<= 1) acc += __shfl_xor(acc, o);
  if ((r & 7) == 0) {
    logbuf[(size_t)e * 8 + h0 + h] = acc;
    atomicMax(&M[d * 8 + h0 + h], encf(acc));
  }
}

// ---------- layer 2: exp(l - max) and segment sum; overwrites logbuf with p ----------
__global__ __launch_bounds__(256) void expsum(float* __restrict__ logbuf,
                                              const unsigned int* __restrict__ M,
                                              float* __restrict__ S,
                                              const int* __restrict__ ei, int E, int ne) {
  int i = blockIdx.x * blockDim.x + threadIdx.x;
  if (i >= ne * 8) return;
  int e = i >> 3, h = i & 7;
  int s, d;
  edge_sd(ei, E, e, s, d);
  float m = decf(M[d * 8 + h]);
  float p = expf(logbuf[i] - m);
  logbuf[i] = p;
  atomicAdd(&S[d * 8 + h], p);
}

// ---------- scatter layer 2, head-blocked, mean over heads ----------
__global__ __launch_bounds__(256) void scatter2(const bf16_t* __restrict__ xl,
                                                const float* __restrict__ logbuf,
                                                const float* __restrict__ S,
                                                const int* __restrict__ ei, int E, int ne,
                                                float* __restrict__ acc,
                                                int h0, int nh) {
  int wave = (int)((blockIdx.x * 256u + threadIdx.x) >> 6);
  int l = threadIdx.x & 63;
  if (wave >= ne) return;
  int s, d;
  edge_sd(ei, E, wave, s, d);
  float al = 0.f;
  if (l < nh) al = logbuf[(size_t)wave * 8 + h0 + l] / (S[d * 8 + h0 + l] + 1e-16f);
  float v = 0.f;
  for (int j = 0; j < nh; ++j) {
    float a = __shfl(al, j);
    v += a * bfu(xl[(size_t)s * (nh * 64) + j * 64 + l]);
  }
  atomicAdd(&acc[(size_t)d * 64 + l], v * 0.125f);
}

// ---------- epilogue layer 2: bias only ----------
__global__ __launch_bounds__(256) void epi2(const float* __restrict__ acc,
                                            const float* __restrict__ b,
                                            float* __restrict__ out, int n) {
  int i = blockIdx.x * blockDim.x + threadIdx.x;
  if (i >= n) return;
  out[i] = acc[i] + b[i & 63];
}

extern "C" void kernel_launch(void* const* d_in, const int* in_sizes, int n_in,
                              void* d_out, int out_size, void* d_ws, size_t ws_size,
                              hipStream_t stream) {
  const float* x = (const float*)d_in[0];
  const int* ei = (const int*)d_in[1];
  const float* Wmat[3][2] = {
      {(const float*)d_in[2], (const float*)d_in[3]},
      {(const float*)d_in[6], (const float*)d_in[7]},
      {(const float*)d_in[10], (const float*)d_in[11]}};
  const float* att[3] = {(const float*)d_in[4], (const float*)d_in[8],
                         (const float*)d_in[12]};
  const float* bias[3] = {(const float*)d_in[5], (const float*)d_in[9],
                          (const float*)d_in[13]};
  int E = in_sizes[1] / 2;
  int ne = E + NNODES;

  // choose layer-2 head-block so workspace fits ws_size (bf16 XL/XR tables)
  int NHB = 8;
  for (;;) {
    size_t bytes = (size_t)NNODES * NHB * 64 * 2 * 2   // XL + XR (bf16)
                 + (size_t)ne * 8 * 4                  // LOG
                 + (size_t)NNODES * 8 * 4 * 2          // M + S
                 + (size_t)NNODES * 64 * 4 * 2;        // CUR + ACC
    if (bytes <= ws_size || NHB == 1) break;
    NHB >>= 1;
  }
  int nblk = 8 / NHB;

  char* base = (char*)d_ws;
  bf16_t* XL = (bf16_t*)base; base += (size_t)NNODES * NHB * 64 * 2;
  bf16_t* XR = (bf16_t*)base; base += (size_t)NNODES * NHB * 64 * 2;
  float* LOG = (float*)base;  base += (size_t)ne * 8 * 4;
  unsigned int* M = (unsigned int*)base; base += (size_t)NNODES * 8 * 4;
  float* S = (float*)base;    base += (size_t)NNODES * 8 * 4;
  float* CUR = (float*)base;  base += (size_t)NNODES * 64 * 4;
  float* ACC = (float*)base;

  const int gx16 = (NNODES + 15) / 16;
  const int eblk = (ne + 3) / 4;  // one wave per edge, 4 waves/block

  // ---------------- layers 0 and 1 (C=8, concat) ----------------
  for (int layer = 0; layer < 2; ++layer) {
    const float* in = (layer == 0) ? x : CUR;
    gemm_cols<<<dim3(gx16, 1), 256, 0, stream>>>(in, Wmat[layer][0], XL, NNODES, 64, 0, 64);
    gemm_cols<<<dim3(gx16, 1), 256, 0, stream>>>(in, Wmat[layer][1], XR, NNODES, 64, 0, 64);
    init_ms<<<(NNODES * 8 + 255) / 256, 256, 0, stream>>>(M, S, NNODES * 8);
    zerof<<<(NNODES * 64 + 255) / 256, 256, 0, stream>>>(ACC, NNODES * 64);

    logits_c8<<<(ne * 8 + 255) / 256, 256, 0, stream>>>(XL, XR, att[layer], ei, E, ne, LOG, M);
    scatter_c8<<<eblk, 256, 0, stream>>>(XL, LOG, M, S, ei, E, ne, ACC);
    epi01<<<(NNODES * 64 + 255) / 256, 256, 0, stream>>>(
        ACC, S, bias[layer], CUR, CUR, NNODES * 64, layer);
  }

  // ---------------- layer 2 (C=64, mean over heads) ----------------
  init_ms<<<(NNODES * 8 + 255) / 256, 256, 0, stream>>>(M, S, NNODES * 8);

  int grp = NHB * 8, epw = 64 / grp;
  int lblk = ((ne + epw - 1) / epw + 3) / 4;
  for (int hb = 0; hb < nblk; ++hb) {
    gemm_cols<<<dim3(gx16, NHB), 256, 0, stream>>>(CUR, Wmat[2][0], XL, NNODES, 512,
                                                   hb * NHB * 64, NHB * 64);
    gemm_cols<<<dim3(gx16, NHB), 256, 0, stream>>>(CUR, Wmat[2][1], XR, NNODES, 512,
                                                   hb * NHB * 64, NHB * 64);
    logits2<<<lblk, 256, 0, stream>>>(XL, XR, att[2], ei, E, ne, LOG, M, hb * NHB, NHB);
  }
  expsum<<<(ne * 8 + 255) / 256, 256, 0, stream>>>(LOG, M, S, ei, E, ne);
  zerof<<<(NNODES * 64 + 255) / 256, 256, 0, stream>>>(ACC, NNODES * 64);
  for (int hb = 0; hb < nblk; ++hb) {
    if (nblk > 1)
      gemm_cols<<<dim3(gx16, NHB), 256, 0, stream>>>(CUR, Wmat[2][0], XL, NNODES, 512,
                                                     hb * NHB * 64, NHB * 64);
    scatter2<<<eblk, 256, 0, stream>>>(XL, LOG, S, ei, E, ne, ACC, hb * NHB, NHB);
  }
  epi2<<<(NNODES * 64 + 255) / 256, 256, 0, stream>>>(ACC, bias[2], (float*)d_out, NNODES * 64);
}

// Round 4
// 1799.656 us; speedup vs baseline: 3.3245x; 2.2564x over previous
//
#include <hip/hip_runtime.h>
#include <math.h>

#define NNODES 100000

typedef unsigned short bf16_t;

// ---------- bf16 helpers ----------
__device__ __forceinline__ float bfu(bf16_t u) { return __uint_as_float(((unsigned)u) << 16); }
__device__ __forceinline__ float bf_lo(unsigned u) { return __uint_as_float(u << 16); }
__device__ __forceinline__ float bf_hi(unsigned u) { return __uint_as_float(u & 0xffff0000u); }
__device__ __forceinline__ bf16_t f2bf(float f) {
  unsigned u = __float_as_uint(f);
  return (bf16_t)((u + 0x7fffu + ((u >> 16) & 1u)) >> 16);
}

// ---------- GEMM: out[n, ncols](bf16) = in[n, 64] @ W[64, col0:col0+ncols] ----------
__global__ __launch_bounds__(256) void gemm_cols(const float* __restrict__ in,
                                                 const float* __restrict__ W,
                                                 bf16_t* __restrict__ out,
                                                 int n, int fo, int col0, int ncols) {
  __shared__ float sW[64][64];
  __shared__ float sX[16][64];
  int ct = blockIdx.y * 64;
  for (int i = threadIdx.x; i < 64 * 64; i += 256) {
    int k = i >> 6, c = i & 63;
    sW[k][c] = W[k * fo + col0 + ct + c];
  }
  int r0 = blockIdx.x * 16;
  for (int i = threadIdx.x; i < 16 * 64; i += 256) {
    int r = i >> 6, k = i & 63;
    sX[r][k] = (r0 + r < n) ? in[(size_t)(r0 + r) * 64 + k] : 0.f;
  }
  __syncthreads();
  int c = threadIdx.x & 63;
  int rr = threadIdx.x >> 6;
#pragma unroll
  for (int rsub = 0; rsub < 4; ++rsub) {
    int r = rr * 4 + rsub;
    float acc = 0.f;
#pragma unroll
    for (int k = 0; k < 64; ++k) acc += sX[r][k] * sW[k][c];
    if (r0 + r < n) out[(size_t)(r0 + r) * ncols + ct + c] = f2bf(acc);
  }
}

// ---------- CSR build ----------
__global__ void zeroi(int* __restrict__ p, int n) {
  int i = blockIdx.x * blockDim.x + threadIdx.x;
  if (i < n) p[i] = 0;
}

__global__ void hist(const int* __restrict__ ei, int E, int* __restrict__ cnt) {
  int e = blockIdx.x * blockDim.x + threadIdx.x;
  if (e < E) atomicAdd(&cnt[ei[E + e]], 1);
}

// per-block inclusive scan of 256 elements
__global__ void scan1(const int* __restrict__ cnt, int n,
                      int* __restrict__ scn, int* __restrict__ bsum) {
  __shared__ int sh[256];
  int t = threadIdx.x, i = blockIdx.x * 256 + t;
  int v = (i < n) ? cnt[i] : 0;
  sh[t] = v;
  __syncthreads();
  for (int off = 1; off < 256; off <<= 1) {
    int x = (t >= off) ? sh[t - off] : 0;
    __syncthreads();
    sh[t] += x;
    __syncthreads();
  }
  if (i < n) scn[i] = sh[t];
  if (t == 255) bsum[blockIdx.x] = sh[255];
}

// single-block inclusive scan of block sums (nb <= 512)
__global__ void scan2(int* __restrict__ bsum, int nb) {
  __shared__ int sh[512];
  int t = threadIdx.x;
  sh[t] = (t < nb) ? bsum[t] : 0;
  __syncthreads();
  for (int off = 1; off < 512; off <<= 1) {
    int x = (t >= off) ? sh[t - off] : 0;
    __syncthreads();
    sh[t] += x;
    __syncthreads();
  }
  if (t < nb) bsum[t] = sh[t];
}

__global__ void scan3(const int* __restrict__ scn, const int* __restrict__ cnt,
                      const int* __restrict__ bsum, int n,
                      int* __restrict__ RS, int* __restrict__ cur) {
  int i = blockIdx.x * blockDim.x + threadIdx.x;
  if (i >= n) return;
  int b = i >> 8;
  int pre = (b > 0) ? bsum[b - 1] : 0;
  int incl = scn[i] + pre;
  RS[i + 1] = incl;
  cur[i] = incl - cnt[i];
  if (i == 0) RS[0] = 0;
}

__global__ void scat(const int* __restrict__ ei, int E,
                     int* __restrict__ cur, int* __restrict__ SRC) {
  int e = blockIdx.x * blockDim.x + threadIdx.x;
  if (e >= E) return;
  int d = ei[E + e];
  int pos = atomicAdd(&cur[d], 1);
  SRC[pos] = ei[e];
}

// ---------- fused layer, C=8 concat (layers 0/1): one wave per dst ----------
// lane l = (head l>>3, channel l&7); logit via 8-lane group reduce;
// online softmax in registers; epilogue (bias, ELU, residual) fused.
__global__ __launch_bounds__(256) void fused01(const bf16_t* __restrict__ xl,
                                               const bf16_t* __restrict__ xr,
                                               const float* __restrict__ att, // [8][8]
                                               const int* __restrict__ RS,
                                               const int* __restrict__ SRC,
                                               const float* __restrict__ bias,
                                               float* __restrict__ curbuf,
                                               int n, int addres) {
  int d = blockIdx.x * 4 + (threadIdx.x >> 6);
  int l = threadIdx.x & 63;
  if (d >= n) return;
  float xr_l = bfu(xr[(size_t)d * 64 + l]);
  float a_l = att[l];
  int rs = RS[d], re = RS[d + 1];
  float m = -1e30f, s = 0.f, acc = 0.f;
  int sidx = d;      // self loop processed first
  int i = rs - 1;
  for (;;) {
    float xl_l = bfu(xl[(size_t)sidx * 64 + l]);
    float v = xl_l + xr_l;
    v = v > 0.f ? v : 0.2f * v;
    float t = v * a_l;
    t += __shfl_xor(t, 1);
    t += __shfl_xor(t, 2);
    t += __shfl_xor(t, 4);
    float nm = fmaxf(m, t);
    float e0 = __expf(m - nm), e1 = __expf(t - nm);
    s = s * e0 + e1;
    acc = acc * e0 + e1 * xl_l;
    m = nm;
    ++i;
    if (i >= re) break;
    sidx = SRC[i];
  }
  float v = acc / s + bias[l];
  v = v > 0.f ? v : expm1f(v);
  if (addres) v += curbuf[(size_t)d * 64 + l];
  curbuf[(size_t)d * 64 + l] = v;
}

// ---------- fused layer 2, 4-head block, mean over heads: one wave per dst ----------
// lane l = bytes [8l, 8l+8) of the 512B row: head l>>4, channels (l&15)*4..+3
__global__ __launch_bounds__(256) void fused2(const bf16_t* __restrict__ xl,
                                              const bf16_t* __restrict__ xr,
                                              const float* __restrict__ att, // [8][64]
                                              const int* __restrict__ RS,
                                              const int* __restrict__ SRC,
                                              const float* __restrict__ bias,
                                              float* __restrict__ accbuf,
                                              float* __restrict__ outbuf,
                                              int n, int h0, int pass) {
  int d = blockIdx.x * 4 + (threadIdx.x >> 6);
  int l = threadIdx.x & 63;
  if (d >= n) return;
  uint2 ur = *(const uint2*)(xr + (size_t)d * 256 + l * 4);
  float xr0 = bf_lo(ur.x), xr1 = bf_hi(ur.x), xr2 = bf_lo(ur.y), xr3 = bf_hi(ur.y);
  int h = l >> 4, c0 = (l & 15) * 4;
  const float* ap = att + (h0 + h) * 64 + c0;
  float a0 = ap[0], a1 = ap[1], a2 = ap[2], a3 = ap[3];
  int rs = RS[d], re = RS[d + 1];
  float m = -1e30f, s = 0.f;
  float ac0 = 0.f, ac1 = 0.f, ac2 = 0.f, ac3 = 0.f;
  int sidx = d;
  int i = rs - 1;
  for (;;) {
    uint2 u = *(const uint2*)(xl + (size_t)sidx * 256 + l * 4);
    float x0 = bf_lo(u.x), x1 = bf_hi(u.x), x2 = bf_lo(u.y), x3 = bf_hi(u.y);
    float v0 = x0 + xr0, v1 = x1 + xr1, v2 = x2 + xr2, v3 = x3 + xr3;
    v0 = v0 > 0.f ? v0 : 0.2f * v0;
    v1 = v1 > 0.f ? v1 : 0.2f * v1;
    v2 = v2 > 0.f ? v2 : 0.2f * v2;
    v3 = v3 > 0.f ? v3 : 0.2f * v3;
    float t = v0 * a0 + v1 * a1 + v2 * a2 + v3 * a3;
    t += __shfl_xor(t, 1);
    t += __shfl_xor(t, 2);
    t += __shfl_xor(t, 4);
    t += __shfl_xor(t, 8);
    float nm = fmaxf(m, t);
    float e0 = __expf(m - nm), e1 = __expf(t - nm);
    s = s * e0 + e1;
    ac0 = ac0 * e0 + e1 * x0;
    ac1 = ac1 * e0 + e1 * x1;
    ac2 = ac2 * e0 + e1 * x2;
    ac3 = ac3 * e0 + e1 * x3;
    m = nm;
    ++i;
    if (i >= re) break;
    sidx = SRC[i];
  }
  float inv = 1.0f / s;
  float r0 = ac0 * inv, r1 = ac1 * inv, r2 = ac2 * inv, r3 = ac3 * inv;
  // sum over the 4 heads of this block (lanes l, l^16, l^32, l^48)
  r0 += __shfl_xor(r0, 16); r0 += __shfl_xor(r0, 32);
  r1 += __shfl_xor(r1, 16); r1 += __shfl_xor(r1, 32);
  r2 += __shfl_xor(r2, 16); r2 += __shfl_xor(r2, 32);
  r3 += __shfl_xor(r3, 16); r3 += __shfl_xor(r3, 32);
  if (l < 16) {
    float4* pa = (float4*)(accbuf + (size_t)d * 64 + l * 4);
    if (pass == 0) {
      *pa = make_float4(r0, r1, r2, r3);
    } else {
      float4 prev = *pa;
      float4 o;
      o.x = (prev.x + r0) * 0.125f + bias[l * 4 + 0];
      o.y = (prev.y + r1) * 0.125f + bias[l * 4 + 1];
      o.z = (prev.z + r2) * 0.125f + bias[l * 4 + 2];
      o.w = (prev.w + r3) * 0.125f + bias[l * 4 + 3];
      *(float4*)(outbuf + (size_t)d * 64 + l * 4) = o;
    }
  }
}

extern "C" void kernel_launch(void* const* d_in, const int* in_sizes, int n_in,
                              void* d_out, int out_size, void* d_ws, size_t ws_size,
                              hipStream_t stream) {
  const float* x = (const float*)d_in[0];
  const int* ei = (const int*)d_in[1];
  const float* Wmat[3][2] = {
      {(const float*)d_in[2], (const float*)d_in[3]},
      {(const float*)d_in[6], (const float*)d_in[7]},
      {(const float*)d_in[10], (const float*)d_in[11]}};
  const float* att[3] = {(const float*)d_in[4], (const float*)d_in[8],
                         (const float*)d_in[12]};
  const float* bias[3] = {(const float*)d_in[5], (const float*)d_in[9],
                          (const float*)d_in[13]};
  const int N = NNODES;
  int E = in_sizes[1] / 2;

  // ---- workspace layout (~161 MB) ----
  char* p = (char*)d_ws;
  auto alloc = [&](size_t bytes) {
    char* r = p;
    p += (bytes + 255) & ~(size_t)255;
    return r;
  };
  float* CUR = (float*)alloc((size_t)N * 64 * 4);
  float* ACC = (float*)alloc((size_t)N * 64 * 4);
  bf16_t* XL = (bf16_t*)alloc((size_t)N * 256 * 2);
  bf16_t* XR = (bf16_t*)alloc((size_t)N * 256 * 2);
  int* RS = (int*)alloc((size_t)(N + 1) * 4);
  int* CNT = (int*)alloc((size_t)N * 4);
  int* CURS = (int*)alloc((size_t)N * 4);
  int* SCN = (int*)alloc((size_t)N * 4);
  int* BSUM = (int*)alloc(512 * 4);
  int* SRC = (int*)alloc((size_t)E * 4);

  const int nb = (N + 255) / 256;   // scan blocks (<=512)
  const int geblk = (E + 255) / 256;
  const int gnode = (N + 3) / 4;    // 4 waves (dsts) per 256-thread block
  const int gx16 = (N + 15) / 16;

  // ---- CSR build (once, shared by all 3 layers) ----
  zeroi<<<nb, 256, 0, stream>>>(CNT, N);
  hist<<<geblk, 256, 0, stream>>>(ei, E, CNT);
  scan1<<<nb, 256, 0, stream>>>(CNT, N, SCN, BSUM);
  scan2<<<1, 512, 0, stream>>>(BSUM, nb);
  scan3<<<nb, 256, 0, stream>>>(SCN, CNT, BSUM, N, RS, CURS);
  scat<<<geblk, 256, 0, stream>>>(ei, E, CURS, SRC);

  // ---- layers 0 and 1 (C=8, concat) ----
  for (int layer = 0; layer < 2; ++layer) {
    const float* in = (layer == 0) ? x : CUR;
    gemm_cols<<<dim3(gx16, 1), 256, 0, stream>>>(in, Wmat[layer][0], XL, N, 64, 0, 64);
    gemm_cols<<<dim3(gx16, 1), 256, 0, stream>>>(in, Wmat[layer][1], XR, N, 64, 0, 64);
    fused01<<<gnode, 256, 0, stream>>>(XL, XR, att[layer], RS, SRC, bias[layer],
                                       CUR, N, layer);
  }

  // ---- layer 2 (C=64, mean over 8 heads; two 4-head passes) ----
  for (int hb = 0; hb < 2; ++hb) {
    gemm_cols<<<dim3(gx16, 4), 256, 0, stream>>>(CUR, Wmat[2][0], XL, N, 512,
                                                 hb * 256, 256);
    gemm_cols<<<dim3(gx16, 4), 256, 0, stream>>>(CUR, Wmat[2][1], XR, N, 512,
                                                 hb * 256, 256);
    fused2<<<gnode, 256, 0, stream>>>(XL, XR, att[2], RS, SRC, bias[2],
                                      ACC, (float*)d_out, N, hb * 4, hb);
  }
}